// Round 4
// baseline (725.863 us; speedup 1.0000x reference)
//
#include <hip/hip_runtime.h>
#include <cfloat>
#include <cmath>

// PillarEncoder (MI355X / gfx950): out[b][c][y][x] = (4, 64, 496, 432) fp32
#define XL 432
#define YL 496
#define NCH 64
#define HIMG 192
#define WIMG 640
#define PTS_M 32

#define WAVES 16            // 1024 threads/block
#define TPB (WAVES * 64)
#define PPG 4               // pillars per wave-group
#define NBLOCKS 256
#define WPITCH 132          // padded weight row pitch (floats); 16B-aligned, bank-spread

__device__ __forceinline__ float rl(float v, int l) {
    // broadcast lane l's value to all lanes via v_readlane (VALU/SALU path, NOT the LDS pipe)
    return __uint_as_float(__builtin_amdgcn_readlane(__float_as_uint(v), l));
}

#define RED5(v) { v += __shfl_xor(v, 16); v += __shfl_xor(v, 8); v += __shfl_xor(v, 4); \
                  v += __shfl_xor(v, 2);  v += __shfl_xor(v, 1); }

__global__ void zerofill(float4* __restrict__ o, int n4) {
    int i = blockIdx.x * blockDim.x + threadIdx.x;
    const int st = gridDim.x * blockDim.x;
    const float4 z = make_float4(0.f, 0.f, 0.f, 0.f);
    for (; i < n4; i += st) o[i] = z;
}

// K1: per-pillar encode + gated MLP. DIRECT=true scatters to canvas (fallback);
// DIRECT=false writes compact feat[P][64] + idxmap (primary).
template<bool DIRECT>
__global__ __launch_bounds__(TPB, 4) void pillar_compute(
    const float* __restrict__ pillars,   // P*32*4
    const int*   __restrict__ coors,     // P*3 (b, ix, iy)
    const int*   __restrict__ npp,       // P
    const float* __restrict__ image,     // B*64*192*640
    const float* __restrict__ calibs,    // B*3*4
    const float* __restrict__ conv_w,    // 64*9
    const float* __restrict__ bng, const float* __restrict__ bnb,
    const float* __restrict__ bnm, const float* __restrict__ bnv,
    const float* __restrict__ w1, const float* __restrict__ b1,
    const float* __restrict__ lng, const float* __restrict__ lnb,
    const float* __restrict__ w2, const float* __restrict__ b2,
    float* __restrict__ feat, int* __restrict__ idxmap,
    float* __restrict__ out, int P)
{
    __shared__ float w1p[128 * WPITCH];      // 66 KB: w1p[j*WPITCH+k] = w1[j][k]
    __shared__ float w2p[64 * WPITCH];       // 33 KB

    const int tid  = threadIdx.x;
    const int lane = tid & 63;
    const int wv   = tid >> 6;

    for (int i = tid; i < 128 * 32; i += TPB) {
        const int j = i >> 5, k4 = i & 31;
        ((float4*)(w1p + j * WPITCH))[k4] = ((const float4*)w1)[i];
    }
    for (int i = tid; i < 64 * 32; i += TPB) {
        const int j = i >> 5, k4 = i & 31;
        ((float4*)(w2p + j * WPITCH))[k4] = ((const float4*)w2)[i];
    }
    __syncthreads();

    // ---- per-channel folded conv+BN constants (lane = channel) ----
    float cw[9];
    #pragma unroll
    for (int i = 0; i < 9; ++i) cw[i] = conv_w[lane * 9 + i];
    const float s   = bng[lane] / sqrtf(bnv[lane] + 1e-3f);
    const float tch = bnb[lane] - bnm[lane] * s;      // BN(0): masked-row value
    const float As  = (cw[0] + cw[4] + cw[7]) * s;
    const float Bs  = (cw[1] + cw[5] + cw[8]) * s;
    const float Cs  = (cw[2] + cw[6]) * s;
    const float Ds  = cw[3] * s;
    const float w07 = (cw[0] + cw[7]) * s;
    const float w18 = (cw[1] + cw[8]) * s;
    const float w4s = cw[4] * s, w5s = cw[5] * s, w6s = cw[6] * s;

    const float b1a = b1[lane], b1b = b1[lane + 64];
    const float lga = lng[lane], lgb = lng[lane + 64];
    const float lba = lnb[lane], lbb = lnb[lane + 64];
    const float gb2 = b2[lane];

    const float4* w1rA = (const float4*)(w1p + lane * WPITCH);
    const float4* w1rB = (const float4*)(w1p + (lane + 64) * WPITCH);
    const float4* w2r  = (const float4*)(w2p + lane * WPITCH);

    const int ntasks = (P + PPG - 1) / PPG;

    for (int grp = blockIdx.x * WAVES + wv; grp < ntasks; grp += NBLOCKS * WAVES) {
        const int pbase = grp * PPG;

        // ---- points -> registers, coalesced. lanes 0-31: pillar0 (qa)/pillar2 (qb);
        //      lanes 32-63: pillar1 (qa)/pillar3 (qb); one float4 = one point. ----
        const float4* pb4 = (const float4*)pillars + (size_t)pbase * PTS_M;
        float4 qa, qb;
        if (pbase + PPG <= P) {
            qa = pb4[lane];
            qb = pb4[lane + 64];
        } else {
            const int lim = (P - pbase) * PTS_M;
            qa = (lane      < lim) ? pb4[lane]      : make_float4(0.f,0.f,0.f,0.f);
            qb = (lane + 64 < lim) ? pb4[lane + 64] : make_float4(0.f,0.f,0.f,0.f);
        }

        int bbv[PPG], ixv[PPG], iyv[PPG], nv[PPG];
        #pragma unroll
        for (int pp = 0; pp < PPG; ++pp) {
            const int p = pbase + pp;
            if (p < P) {
                bbv[pp] = coors[p * 3]; ixv[pp] = coors[p * 3 + 1];
                iyv[pp] = coors[p * 3 + 2]; nv[pp] = npp[p];
            } else { bbv[pp] = 0; ixv[pp] = 0; iyv[pp] = 0; nv[pp] = 1; }
        }

        // ---- means: half-wave reductions (invalid points are zero in data) ----
        float ax = qa.x, ay = qa.y, az = qa.z;
        float bx = qb.x, by = qb.y, bz = qb.z;
        RED5(ax) RED5(ay) RED5(az)
        RED5(bx) RED5(by) RED5(bz)
        const float axo = __shfl_xor(ax, 32), ayo = __shfl_xor(ay, 32), azo = __shfl_xor(az, 32);
        const float bxo = __shfl_xor(bx, 32), byo = __shfl_xor(by, 32), bzo = __shfl_xor(bz, 32);
        const bool lo = lane < 32;
        float mx[PPG], my[PPG], mz[PPG];
        {
            const float f0 = 1.f / (float)nv[0], f1 = 1.f / (float)nv[1];
            const float f2 = 1.f / (float)nv[2], f3 = 1.f / (float)nv[3];
            mx[0] = (lo ? ax : axo) * f0;  mx[1] = (lo ? axo : ax) * f1;
            my[0] = (lo ? ay : ayo) * f0;  my[1] = (lo ? ayo : ay) * f1;
            mz[0] = (lo ? az : azo) * f0;  mz[1] = (lo ? azo : az) * f1;
            mx[2] = (lo ? bx : bxo) * f2;  mx[3] = (lo ? bxo : bx) * f3;
            my[2] = (lo ? by : byo) * f2;  my[3] = (lo ? byo : by) * f3;
            mz[2] = (lo ? bz : bzo) * f2;  mz[3] = (lo ? bzo : bz) * f3;
        }

        // ---- projection + image gather issue (consumed ~2000cy later) + folded bias ----
        float img[PPG], Es[PPG];
        #pragma unroll
        for (int pp = 0; pp < PPG; ++pp) {
            const float* cb = calibs + bbv[pp] * 12;
            const float pr0 = cb[0]*mx[pp] + cb[1]*my[pp] + cb[2]*mz[pp] + cb[3];
            const float pr1 = cb[4]*mx[pp] + cb[5]*my[pp] + cb[6]*mz[pp] + cb[7];
            const float pr2 = cb[8]*mx[pp] + cb[9]*my[pp] + cb[10]*mz[pp] + cb[11];
            float uf = (pr0 / pr2) * 0.5f;
            float vf = (pr1 / pr2) * 0.5f;
            uf = fminf(fmaxf(uf, 0.f), (float)(WIMG - 1));
            vf = fminf(fmaxf(vf, 0.f), (float)(HIMG - 1));
            const int u = (int)uf, v = (int)vf;
            img[pp] = image[(((size_t)(bbv[pp] * NCH + lane)) * HIMG + v) * WIMG + u];

            const float cxp = (float)ixv[pp] * 0.16f + 0.08f;
            const float cyp = (float)iyv[pp] * 0.16f + (-39.6f);
            Es[pp] = tch - (cxp * w07 + cyp * w18 + mx[pp] * w4s + my[pp] * w5s + mz[pp] * w6s);
        }

        // ---- pooled max: readlane point broadcasts (no LDS) ----
        float pooled[PPG];
        #pragma unroll
        for (int pp = 0; pp < PPG; ++pp) {
            const float4& qr = (pp < 2) ? qa : qb;
            const int lb = (pp & 1) * 32;
            const int n = nv[pp];
            float p0 = (n < PTS_M) ? tch : -FLT_MAX;
            float p1 = -FLT_MAX, p2 = -FLT_MAX, p3 = -FLT_MAX;
            #pragma unroll
            for (int m = 0; m < PTS_M; m += 4) {
                const float h0 = Es[pp] + rl(qr.x,lb+m  )*As + rl(qr.y,lb+m  )*Bs + rl(qr.z,lb+m  )*Cs + rl(qr.w,lb+m  )*Ds;
                const float h1 = Es[pp] + rl(qr.x,lb+m+1)*As + rl(qr.y,lb+m+1)*Bs + rl(qr.z,lb+m+1)*Cs + rl(qr.w,lb+m+1)*Ds;
                const float h2 = Es[pp] + rl(qr.x,lb+m+2)*As + rl(qr.y,lb+m+2)*Bs + rl(qr.z,lb+m+2)*Cs + rl(qr.w,lb+m+2)*Ds;
                const float h3 = Es[pp] + rl(qr.x,lb+m+3)*As + rl(qr.y,lb+m+3)*Bs + rl(qr.z,lb+m+3)*Cs + rl(qr.w,lb+m+3)*Ds;
                p0 = fmaxf(p0, (m     < n) ? h0 : -FLT_MAX);
                p1 = fmaxf(p1, (m + 1 < n) ? h1 : -FLT_MAX);
                p2 = fmaxf(p2, (m + 2 < n) ? h2 : -FLT_MAX);
                p3 = fmaxf(p3, (m + 3 < n) ? h3 : -FLT_MAX);
            }
            pooled[pp] = fmaxf(fmaxf(fmaxf(p0, p1), fmaxf(p2, p3)), 0.f);  // relu∘max
        }

        // ---- GEMM1: LDS only for weights (b128); cat broadcast via readlane ----
        float accA[PPG], accB[PPG];
        #pragma unroll
        for (int pp = 0; pp < PPG; ++pp) { accA[pp] = b1a; accB[pp] = b1b; }
        #pragma unroll
        for (int k4 = 0; k4 < 16; ++k4) {          // k = 0..63: cat = pooled
            const float4 wa = w1rA[k4];
            const float4 wb = w1rB[k4];
            #pragma unroll
            for (int pp = 0; pp < PPG; ++pp) {
                const float s0 = rl(pooled[pp], 4*k4+0), s1 = rl(pooled[pp], 4*k4+1);
                const float s2 = rl(pooled[pp], 4*k4+2), s3 = rl(pooled[pp], 4*k4+3);
                accA[pp] += s0*wa.x + s1*wa.y + s2*wa.z + s3*wa.w;
                accB[pp] += s0*wb.x + s1*wb.y + s2*wb.z + s3*wb.w;
            }
        }
        #pragma unroll
        for (int k4 = 0; k4 < 16; ++k4) {          // k = 64..127: cat = img
            const float4 wa = w1rA[16 + k4];
            const float4 wb = w1rB[16 + k4];
            #pragma unroll
            for (int pp = 0; pp < PPG; ++pp) {
                const float s0 = rl(img[pp], 4*k4+0), s1 = rl(img[pp], 4*k4+1);
                const float s2 = rl(img[pp], 4*k4+2), s3 = rl(img[pp], 4*k4+3);
                accA[pp] += s0*wa.x + s1*wa.y + s2*wa.z + s3*wa.w;
                accB[pp] += s0*wb.x + s1*wb.y + s2*wb.z + s3*wb.w;
            }
        }

        // ---- LayerNorm(128) + relu (in registers) ----
        float gA[PPG], gB[PPG];
        {
            float sum[PPG], sq[PPG];
            #pragma unroll
            for (int pp = 0; pp < PPG; ++pp) {
                sum[pp] = accA[pp] + accB[pp];
                sq[pp]  = accA[pp]*accA[pp] + accB[pp]*accB[pp];
            }
            #pragma unroll
            for (int d = 32; d; d >>= 1) {
                #pragma unroll
                for (int pp = 0; pp < PPG; ++pp) {
                    sum[pp] += __shfl_xor(sum[pp], d);
                    sq[pp]  += __shfl_xor(sq[pp], d);
                }
            }
            #pragma unroll
            for (int pp = 0; pp < PPG; ++pp) {
                const float mu  = sum[pp] * (1.f / 128.f);
                const float var = sq[pp] * (1.f / 128.f) - mu * mu;
                const float inv = 1.f / sqrtf(var + 1e-5f);
                gA[pp] = fmaxf((accA[pp] - mu) * inv * lga + lba, 0.f);
                gB[pp] = fmaxf((accB[pp] - mu) * inv * lgb + lbb, 0.f);
            }
        }

        // ---- GEMM2 (readlane g) + gate ----
        float ac2[PPG];
        #pragma unroll
        for (int pp = 0; pp < PPG; ++pp) ac2[pp] = gb2;
        #pragma unroll
        for (int k4 = 0; k4 < 16; ++k4) {
            const float4 w = w2r[k4];
            #pragma unroll
            for (int pp = 0; pp < PPG; ++pp) {
                ac2[pp] += rl(gA[pp],4*k4+0)*w.x + rl(gA[pp],4*k4+1)*w.y
                         + rl(gA[pp],4*k4+2)*w.z + rl(gA[pp],4*k4+3)*w.w;
            }
        }
        #pragma unroll
        for (int k4 = 0; k4 < 16; ++k4) {
            const float4 w = w2r[16 + k4];
            #pragma unroll
            for (int pp = 0; pp < PPG; ++pp) {
                ac2[pp] += rl(gB[pp],4*k4+0)*w.x + rl(gB[pp],4*k4+1)*w.y
                         + rl(gB[pp],4*k4+2)*w.z + rl(gB[pp],4*k4+3)*w.w;
            }
        }

        #pragma unroll
        for (int pp = 0; pp < PPG; ++pp) {
            const int p = pbase + pp;
            if (p >= P) continue;
            const float gate = 1.f / (1.f + expf(-ac2[pp]));
            const float gf = pooled[pp] * gate + img[pp] * (1.f - gate);
            if (DIRECT) {
                out[(((bbv[pp] * NCH) + lane) * YL + iyv[pp]) * XL + ixv[pp]] = gf;
            } else {
                feat[(size_t)p * NCH + lane] = gf;              // coalesced 256B
                if (lane == 0)
                    idxmap[(bbv[pp] * YL + iyv[pp]) * XL + ixv[pp]] = p + 1;
            }
        }
    }
}

// K2: stream the full canvas with full-line stores (fuses zero-fill).
__global__ __launch_bounds__(256) void canvas_build(
    const float* __restrict__ feat, const int* __restrict__ idxmap,
    float4* __restrict__ out)
{
    __shared__ int idxrow[XL];
    const int by = blockIdx.x;              // b*YL + y
    const int b = by / YL, y = by % YL;
    const int* irow = idxmap + (size_t)by * XL;
    for (int i = threadIdx.x; i < XL; i += 256) idxrow[i] = irow[i];
    __syncthreads();

    const int NF4 = XL / 4;                 // 108
    for (int t = threadIdx.x; t < NCH * NF4; t += 256) {
        const int c = t / NF4, x4 = t - c * NF4;
        const int i0 = idxrow[x4*4+0], i1 = idxrow[x4*4+1];
        const int i2 = idxrow[x4*4+2], i3 = idxrow[x4*4+3];
        float4 o = make_float4(0.f, 0.f, 0.f, 0.f);
        if (i0) o.x = feat[(size_t)(i0-1) * NCH + c];
        if (i1) o.y = feat[(size_t)(i1-1) * NCH + c];
        if (i2) o.z = feat[(size_t)(i2-1) * NCH + c];
        if (i3) o.w = feat[(size_t)(i3-1) * NCH + c];
        out[((size_t)(b * NCH + c) * YL + y) * NF4 + x4] = o;
    }
}

extern "C" void kernel_launch(void* const* d_in, const int* in_sizes, int n_in,
                              void* d_out, int out_size, void* d_ws, size_t ws_size,
                              hipStream_t stream)
{
    const float* pillars = (const float*)d_in[0];
    const int*   coors   = (const int*)d_in[1];
    const int*   npp     = (const int*)d_in[2];
    const float* image   = (const float*)d_in[3];
    const float* calibs  = (const float*)d_in[4];
    const float* conv_w  = (const float*)d_in[6];
    const float* bng     = (const float*)d_in[7];
    const float* bnb     = (const float*)d_in[8];
    const float* bnm     = (const float*)d_in[9];
    const float* bnv     = (const float*)d_in[10];
    const float* w1      = (const float*)d_in[11];
    const float* b1      = (const float*)d_in[12];
    const float* lng     = (const float*)d_in[13];
    const float* lnb     = (const float*)d_in[14];
    const float* w2      = (const float*)d_in[15];
    const float* b2      = (const float*)d_in[16];
    float* out = (float*)d_out;
    const int P = in_sizes[0] / (PTS_M * 4);
    const int B = in_sizes[3] / (NCH * HIMG * WIMG);

    const size_t featBytes = (size_t)P * NCH * sizeof(float);        // 10.24 MB
    const size_t idxBytes  = (size_t)B * YL * XL * sizeof(int);      // 3.43 MB

    if (ws_size >= featBytes + idxBytes) {
        float* feat = (float*)d_ws;
        int* idxmap = (int*)((char*)d_ws + featBytes);
        hipMemsetAsync(idxmap, 0, idxBytes, stream);
        pillar_compute<false><<<dim3(NBLOCKS), dim3(TPB), 0, stream>>>(
            pillars, coors, npp, image, calibs, conv_w, bng, bnb, bnm, bnv,
            w1, b1, lng, lnb, w2, b2, feat, idxmap, nullptr, P);
        canvas_build<<<dim3(B * YL), dim3(256), 0, stream>>>(feat, idxmap, (float4*)d_out);
    } else {
        zerofill<<<dim3(2048), dim3(256), 0, stream>>>((float4*)d_out, out_size / 4);
        pillar_compute<true><<<dim3(NBLOCKS), dim3(TPB), 0, stream>>>(
            pillars, coors, npp, image, calibs, conv_w, bng, bnb, bnm, bnv,
            w1, b1, lng, lnb, w2, b2, nullptr, nullptr, out, P);
    }
}

// Round 5
// 211.977 us; speedup vs baseline: 3.4243x; 3.4243x over previous
//
#include <hip/hip_runtime.h>
#include <cfloat>
#include <cmath>

// PillarEncoder (MI355X / gfx950): out[b][c][y][x] = (4, 64, 496, 432) fp32
#define XL 432
#define YL 496
#define NCH 64
#define HIMG 192
#define WIMG 640
#define HW (HIMG * WIMG)     // 122880
#define PTS_M 32

#define WAVES 16             // 1024 threads/block
#define TPB (WAVES * 64)
#define PPG 4                // pillars per wave-group
#define NBLOCKS 256
#define WPITCH 132           // padded weight row pitch (floats)

typedef const __attribute__((address_space(1))) void* gas_t;
typedef __attribute__((address_space(3))) void* las_t;

__device__ __forceinline__ void gload_lds16(const float* g, float* l) {
    __builtin_amdgcn_global_load_lds((gas_t)g, (las_t)l, 16, 0, 0);
}

#define RED5(v) { v += __shfl_xor(v, 16); v += __shfl_xor(v, 8); v += __shfl_xor(v, 4); \
                  v += __shfl_xor(v, 2);  v += __shfl_xor(v, 1); }

__global__ void zerofill(float4* __restrict__ o, int n4) {
    int i = blockIdx.x * blockDim.x + threadIdx.x;
    const int st = gridDim.x * blockDim.x;
    const float4 z = make_float4(0.f, 0.f, 0.f, 0.f);
    for (; i < n4; i += st) o[i] = z;
}

// K0: image [B][64][H][W] -> imgT [B][H][W][64]  (makes K1's gather coalesced)
__global__ __launch_bounds__(256) void transpose_cl(
    const float* __restrict__ img, float* __restrict__ imgT)
{
    __shared__ float t[64 * 257];            // +1 pad: conflict-free both phases
    const int b    = blockIdx.x / (HW / 256);
    const int tile = blockIdx.x % (HW / 256);
    const int hw0  = tile * 256;
    const int tid  = threadIdx.x;

    const float* base = img + (size_t)b * NCH * HW + hw0;
    #pragma unroll 4
    for (int c = 0; c < 64; ++c)
        t[c * 257 + tid] = base[(size_t)c * HW + tid];   // 1KB coalesced read / iter
    __syncthreads();

    float* ob = imgT + ((size_t)b * HW + hw0) * NCH;
    const int c = tid & 63, r = tid >> 6;
    #pragma unroll 4
    for (int it = 0; it < 64; ++it) {
        const int hw = it * 4 + r;
        ob[hw * 64 + c] = t[c * 257 + hw];               // 1KB coalesced write / iter
    }
}

// K1: encode + gated MLP. MODE 0: direct canvas scatter, plane-major image (full fallback)
//                         MODE 1: feat/idxmap out, plane-major image
//                         MODE 2: feat/idxmap out, channel-last imgT (primary)
template<int MODE>
__global__ __launch_bounds__(TPB, 4) void pillar_compute(
    const float* __restrict__ pillars, const int* __restrict__ coors,
    const int* __restrict__ npp, const float* __restrict__ image,
    const float* __restrict__ calibs, const float* __restrict__ conv_w,
    const float* __restrict__ bng, const float* __restrict__ bnb,
    const float* __restrict__ bnm, const float* __restrict__ bnv,
    const float* __restrict__ w1, const float* __restrict__ b1,
    const float* __restrict__ lng, const float* __restrict__ lnb,
    const float* __restrict__ w2, const float* __restrict__ b2,
    float* __restrict__ feat, int* __restrict__ idxmap,
    float* __restrict__ out, int P)
{
    __shared__ float w1p[128 * WPITCH];      // 66 KB: w1p[j*WPITCH+k] = w1[j][k]
    __shared__ float w2p[64 * WPITCH];       // 33 KB
    __shared__ float ws[WAVES][512];         // 2 KB/wave: points -> cat -> g

    const int tid  = threadIdx.x;
    const int lane = tid & 63;
    const int wv   = tid >> 6;

    for (int i = tid; i < 128 * 32; i += TPB) {
        const int j = i >> 5, k4 = i & 31;
        ((float4*)(w1p + j * WPITCH))[k4] = ((const float4*)w1)[i];
    }
    for (int i = tid; i < 64 * 32; i += TPB) {
        const int j = i >> 5, k4 = i & 31;
        ((float4*)(w2p + j * WPITCH))[k4] = ((const float4*)w2)[i];
    }
    __syncthreads();

    // ---- per-channel folded conv+BN constants (lane = channel) ----
    float cw[9];
    #pragma unroll
    for (int i = 0; i < 9; ++i) cw[i] = conv_w[lane * 9 + i];
    const float s   = bng[lane] / sqrtf(bnv[lane] + 1e-3f);
    const float tch = bnb[lane] - bnm[lane] * s;      // BN(0): masked-row value
    const float As  = (cw[0] + cw[4] + cw[7]) * s;
    const float Bs  = (cw[1] + cw[5] + cw[8]) * s;
    const float Cs  = (cw[2] + cw[6]) * s;
    const float Ds  = cw[3] * s;
    const float w07 = (cw[0] + cw[7]) * s;
    const float w18 = (cw[1] + cw[8]) * s;
    const float w4s = cw[4] * s, w5s = cw[5] * s, w6s = cw[6] * s;

    const float b1a = b1[lane], b1b = b1[lane + 64];
    const float lga = lng[lane], lgb = lng[lane + 64];
    const float lba = lnb[lane], lbb = lnb[lane + 64];
    const float gb2 = b2[lane];

    float* wsw = ws[wv];
    const float4* wsf4 = (const float4*)wsw;
    const float4* w1rA = (const float4*)(w1p + lane * WPITCH);
    const float4* w1rB = (const float4*)(w1p + (lane + 64) * WPITCH);
    const float4* w2r  = (const float4*)(w2p + lane * WPITCH);

    const int ntasks = (P + PPG - 1) / PPG;

    for (int grp = blockIdx.x * WAVES + wv; grp < ntasks; grp += NBLOCKS * WAVES) {
        const int pbase = grp * PPG;
        const bool full = (pbase + PPG <= P);

        // ---------- stage 4 pillars' points (2 KB) into ws ----------
        asm volatile("s_waitcnt lgkmcnt(0)" ::: "memory");  // prior-iter LDS reads done
        if (full) {
            const float* src = pillars + (size_t)pbase * (PTS_M * 4);
            gload_lds16(src + lane * 4, wsw);
            gload_lds16(src + 256 + lane * 4, wsw + 256);
        } else {
            #pragma unroll
            for (int h = 0; h < 2; ++h) {
                const int idx = pbase * PTS_M + h * 64 + lane;
                float4 v = make_float4(0.f, 0.f, 0.f, 0.f);
                if (idx < P * PTS_M) v = ((const float4*)pillars)[idx];
                ((float4*)wsw)[h * 64 + lane] = v;
            }
        }

        int bbv[PPG], ixv[PPG], iyv[PPG], nv[PPG];
        #pragma unroll
        for (int pp = 0; pp < PPG; ++pp) {
            const int p = pbase + pp;
            if (p < P) {
                bbv[pp] = coors[p * 3]; ixv[pp] = coors[p * 3 + 1];
                iyv[pp] = coors[p * 3 + 2]; nv[pp] = npp[p];
            } else { bbv[pp] = 0; ixv[pp] = 0; iyv[pp] = 0; nv[pp] = 1; }
        }

        asm volatile("s_waitcnt vmcnt(0) lgkmcnt(0)" ::: "memory");  // points in LDS

        // ---------- means: pairwise half-wave reductions ----------
        const float4 qa = wsf4[lane];
        const float4 qb = wsf4[64 + lane];
        float ax = qa.x, ay = qa.y, az = qa.z;
        float bx = qb.x, by = qb.y, bz = qb.z;
        RED5(ax) RED5(ay) RED5(az)
        RED5(bx) RED5(by) RED5(bz)
        const float axo = __shfl_xor(ax, 32), ayo = __shfl_xor(ay, 32), azo = __shfl_xor(az, 32);
        const float bxo = __shfl_xor(bx, 32), byo = __shfl_xor(by, 32), bzo = __shfl_xor(bz, 32);
        const bool lo = lane < 32;
        float mx[PPG], my[PPG], mz[PPG];
        {
            const float f0 = 1.f / (float)nv[0], f1 = 1.f / (float)nv[1];
            const float f2 = 1.f / (float)nv[2], f3 = 1.f / (float)nv[3];
            mx[0] = (lo ? ax : axo) * f0;  mx[1] = (lo ? axo : ax) * f1;
            my[0] = (lo ? ay : ayo) * f0;  my[1] = (lo ? ayo : ay) * f1;
            mz[0] = (lo ? az : azo) * f0;  mz[1] = (lo ? azo : az) * f1;
            mx[2] = (lo ? bx : bxo) * f2;  mx[3] = (lo ? bxo : bx) * f3;
            my[2] = (lo ? by : byo) * f2;  my[3] = (lo ? byo : by) * f3;
            mz[2] = (lo ? bz : bzo) * f2;  mz[3] = (lo ? bzo : bz) * f3;
        }

        // ---------- projection + image gather issue + folded bias ----------
        float img[PPG], Es[PPG];
        #pragma unroll
        for (int pp = 0; pp < PPG; ++pp) {
            const float* cb = calibs + bbv[pp] * 12;
            const float pr0 = cb[0]*mx[pp] + cb[1]*my[pp] + cb[2]*mz[pp] + cb[3];
            const float pr1 = cb[4]*mx[pp] + cb[5]*my[pp] + cb[6]*mz[pp] + cb[7];
            const float pr2 = cb[8]*mx[pp] + cb[9]*my[pp] + cb[10]*mz[pp] + cb[11];
            float uf = (pr0 / pr2) * 0.5f;
            float vf = (pr1 / pr2) * 0.5f;
            uf = fminf(fmaxf(uf, 0.f), (float)(WIMG - 1));
            vf = fminf(fmaxf(vf, 0.f), (float)(HIMG - 1));
            const int u = (int)uf, v = (int)vf;
            if (MODE == 2) {
                // channel-last: 64 lanes read 256 contiguous bytes (coalesced)
                img[pp] = image[((size_t)bbv[pp] * HW + (size_t)v * WIMG + u) * NCH + lane];
            } else {
                img[pp] = image[(((size_t)(bbv[pp] * NCH + lane)) * HIMG + v) * WIMG + u];
            }
            const float cxp = (float)ixv[pp] * 0.16f + 0.08f;
            const float cyp = (float)iyv[pp] * 0.16f + (-39.6f);
            Es[pp] = tch - (cxp * w07 + cyp * w18 + mx[pp] * w4s + my[pp] * w5s + mz[pp] * w6s);
        }

        // ---------- pooled max: LDS broadcast reads ----------
        float pooled[PPG];
        #pragma unroll
        for (int pp = 0; pp < PPG; ++pp) {
            const int n = nv[pp];
            float p0 = (n < PTS_M) ? tch : -FLT_MAX;
            float p1 = -FLT_MAX, p2 = -FLT_MAX, p3 = -FLT_MAX;
            #pragma unroll
            for (int m = 0; m < PTS_M; m += 4) {
                const float4 q0 = wsf4[pp * 32 + m];
                const float4 q1 = wsf4[pp * 32 + m + 1];
                const float4 q2 = wsf4[pp * 32 + m + 2];
                const float4 q3 = wsf4[pp * 32 + m + 3];
                const float h0 = Es[pp] + q0.x*As + q0.y*Bs + q0.z*Cs + q0.w*Ds;
                const float h1 = Es[pp] + q1.x*As + q1.y*Bs + q1.z*Cs + q1.w*Ds;
                const float h2 = Es[pp] + q2.x*As + q2.y*Bs + q2.z*Cs + q2.w*Ds;
                const float h3 = Es[pp] + q3.x*As + q3.y*Bs + q3.z*Cs + q3.w*Ds;
                p0 = fmaxf(p0, (m     < n) ? h0 : -FLT_MAX);
                p1 = fmaxf(p1, (m + 1 < n) ? h1 : -FLT_MAX);
                p2 = fmaxf(p2, (m + 2 < n) ? h2 : -FLT_MAX);
                p3 = fmaxf(p3, (m + 3 < n) ? h3 : -FLT_MAX);
            }
            pooled[pp] = fmaxf(fmaxf(fmaxf(p0, p1), fmaxf(p2, p3)), 0.f);
        }

        // ---------- cat -> ws ----------
        #pragma unroll
        for (int pp = 0; pp < PPG; ++pp) {
            wsw[pp * 128 + lane]      = pooled[pp];
            wsw[pp * 128 + 64 + lane] = img[pp];
        }
        asm volatile("s_waitcnt lgkmcnt(0)" ::: "memory");

        // ---------- GEMM1 ----------
        float accA[PPG], accB[PPG];
        #pragma unroll
        for (int pp = 0; pp < PPG; ++pp) { accA[pp] = b1a; accB[pp] = b1b; }
        #pragma unroll 4
        for (int k4 = 0; k4 < 32; ++k4) {
            const float4 wa = w1rA[k4];
            const float4 wb = w1rB[k4];
            #pragma unroll
            for (int pp = 0; pp < PPG; ++pp) {
                const float4 cv = wsf4[pp * 32 + k4];
                accA[pp] += cv.x*wa.x + cv.y*wa.y + cv.z*wa.z + cv.w*wa.w;
                accB[pp] += cv.x*wb.x + cv.y*wb.y + cv.z*wb.z + cv.w*wb.w;
            }
        }

        // ---------- LayerNorm(128) + relu -> ws ----------
        float sum[PPG], sq[PPG];
        #pragma unroll
        for (int pp = 0; pp < PPG; ++pp) {
            sum[pp] = accA[pp] + accB[pp];
            sq[pp]  = accA[pp]*accA[pp] + accB[pp]*accB[pp];
        }
        #pragma unroll
        for (int d = 32; d; d >>= 1) {
            #pragma unroll
            for (int pp = 0; pp < PPG; ++pp) {
                sum[pp] += __shfl_xor(sum[pp], d);
                sq[pp]  += __shfl_xor(sq[pp], d);
            }
        }
        #pragma unroll
        for (int pp = 0; pp < PPG; ++pp) {
            const float mu  = sum[pp] * (1.f / 128.f);
            const float var = sq[pp] * (1.f / 128.f) - mu * mu;
            const float inv = 1.f / sqrtf(var + 1e-5f);
            const float g0 = (accA[pp] - mu) * inv * lga + lba;
            const float g1 = (accB[pp] - mu) * inv * lgb + lbb;
            wsw[pp * 128 + lane]      = fmaxf(g0, 0.f);
            wsw[pp * 128 + 64 + lane] = fmaxf(g1, 0.f);
        }
        asm volatile("s_waitcnt lgkmcnt(0)" ::: "memory");

        // ---------- GEMM2 + gate + output ----------
        float ac2[PPG];
        #pragma unroll
        for (int pp = 0; pp < PPG; ++pp) ac2[pp] = gb2;
        #pragma unroll 4
        for (int k4 = 0; k4 < 32; ++k4) {
            const float4 w = w2r[k4];
            #pragma unroll
            for (int pp = 0; pp < PPG; ++pp) {
                const float4 gv = wsf4[pp * 32 + k4];
                ac2[pp] += gv.x*w.x + gv.y*w.y + gv.z*w.z + gv.w*w.w;
            }
        }
        #pragma unroll
        for (int pp = 0; pp < PPG; ++pp) {
            const int p = pbase + pp;
            if (p >= P) continue;
            const float gate = 1.f / (1.f + expf(-ac2[pp]));
            const float gf = pooled[pp] * gate + img[pp] * (1.f - gate);
            if (MODE == 0) {
                out[(((bbv[pp] * NCH) + lane) * YL + iyv[pp]) * XL + ixv[pp]] = gf;
            } else {
                feat[(size_t)p * NCH + lane] = gf;              // coalesced 256B
                if (lane == 0)
                    idxmap[(bbv[pp] * YL + iyv[pp]) * XL + ixv[pp]] = p + 1;
            }
        }
    }
}

// K2: stream the canvas with full-line stores (fuses zero-fill; no RFO grain)
__global__ __launch_bounds__(256) void canvas_build(
    const float* __restrict__ feat, const int* __restrict__ idxmap,
    float4* __restrict__ out)
{
    __shared__ int idxrow[XL];
    const int by = blockIdx.x;              // b*YL + y
    const int b = by / YL, y = by % YL;
    const int* irow = idxmap + (size_t)by * XL;
    for (int i = threadIdx.x; i < XL; i += 256) idxrow[i] = irow[i];
    __syncthreads();

    const int NF4 = XL / 4;                 // 108
    for (int t = threadIdx.x; t < NCH * NF4; t += 256) {
        const int c = t / NF4, x4 = t - c * NF4;
        const int i0 = idxrow[x4*4+0], i1 = idxrow[x4*4+1];
        const int i2 = idxrow[x4*4+2], i3 = idxrow[x4*4+3];
        float4 o = make_float4(0.f, 0.f, 0.f, 0.f);
        if (i0) o.x = feat[(size_t)(i0-1) * NCH + c];
        if (i1) o.y = feat[(size_t)(i1-1) * NCH + c];
        if (i2) o.z = feat[(size_t)(i2-1) * NCH + c];
        if (i3) o.w = feat[(size_t)(i3-1) * NCH + c];
        out[((size_t)(b * NCH + c) * YL + y) * NF4 + x4] = o;
    }
}

extern "C" void kernel_launch(void* const* d_in, const int* in_sizes, int n_in,
                              void* d_out, int out_size, void* d_ws, size_t ws_size,
                              hipStream_t stream)
{
    const float* pillars = (const float*)d_in[0];
    const int*   coors   = (const int*)d_in[1];
    const int*   npp     = (const int*)d_in[2];
    const float* image   = (const float*)d_in[3];
    const float* calibs  = (const float*)d_in[4];
    const float* conv_w  = (const float*)d_in[6];
    const float* bng     = (const float*)d_in[7];
    const float* bnb     = (const float*)d_in[8];
    const float* bnm     = (const float*)d_in[9];
    const float* bnv     = (const float*)d_in[10];
    const float* w1      = (const float*)d_in[11];
    const float* b1      = (const float*)d_in[12];
    const float* lng     = (const float*)d_in[13];
    const float* lnb     = (const float*)d_in[14];
    const float* w2      = (const float*)d_in[15];
    const float* b2      = (const float*)d_in[16];
    float* out = (float*)d_out;
    const int P = in_sizes[0] / (PTS_M * 4);
    const int B = in_sizes[3] / (NCH * HW);

    const size_t featBytes = (size_t)P * NCH * sizeof(float);        // 10.24 MB
    const size_t idxBytes  = (size_t)B * YL * XL * sizeof(int);      //  3.43 MB
    const size_t imgTBytes = (size_t)B * HW * NCH * sizeof(float);   // 125.8 MB

    if (ws_size >= featBytes + idxBytes + imgTBytes) {
        float* feat   = (float*)d_ws;
        int*   idxmap = (int*)((char*)d_ws + featBytes);
        float* imgT   = (float*)((char*)d_ws + featBytes + idxBytes);
        hipMemsetAsync(idxmap, 0, idxBytes, stream);
        transpose_cl<<<dim3(B * (HW / 256)), dim3(256), 0, stream>>>(image, imgT);
        pillar_compute<2><<<dim3(NBLOCKS), dim3(TPB), 0, stream>>>(
            pillars, coors, npp, imgT, calibs, conv_w, bng, bnb, bnm, bnv,
            w1, b1, lng, lnb, w2, b2, feat, idxmap, nullptr, P);
        canvas_build<<<dim3(B * YL), dim3(256), 0, stream>>>(feat, idxmap, (float4*)d_out);
    } else if (ws_size >= featBytes + idxBytes) {
        float* feat   = (float*)d_ws;
        int*   idxmap = (int*)((char*)d_ws + featBytes);
        hipMemsetAsync(idxmap, 0, idxBytes, stream);
        pillar_compute<1><<<dim3(NBLOCKS), dim3(TPB), 0, stream>>>(
            pillars, coors, npp, image, calibs, conv_w, bng, bnb, bnm, bnv,
            w1, b1, lng, lnb, w2, b2, feat, idxmap, nullptr, P);
        canvas_build<<<dim3(B * YL), dim3(256), 0, stream>>>(feat, idxmap, (float4*)d_out);
    } else {
        zerofill<<<dim3(2048), dim3(256), 0, stream>>>((float4*)d_out, out_size / 4);
        pillar_compute<0><<<dim3(NBLOCKS), dim3(TPB), 0, stream>>>(
            pillars, coors, npp, image, calibs, conv_w, bng, bnb, bnm, bnv,
            w1, b1, lng, lnb, w2, b2, nullptr, nullptr, out, P);
    }
}

// Round 6
// 210.455 us; speedup vs baseline: 3.4490x; 1.0072x over previous
//
#include <hip/hip_runtime.h>
#include <cfloat>
#include <cmath>

// PillarEncoder (MI355X / gfx950): out[b][c][y][x] = (4, 64, 496, 432) fp32
#define XL 432
#define YL 496
#define NCH 64
#define HIMG 192
#define WIMG 640
#define HW (HIMG * WIMG)     // 122880
#define PTS_M 32

#define WAVES 16             // 1024 threads/block
#define TPB (WAVES * 64)
#define PPG 4                // pillars per wave-group
#define NBLOCKS 256
#define WPITCH 132           // padded weight row pitch (floats)

typedef const __attribute__((address_space(1))) void* gas_t;
typedef __attribute__((address_space(3))) void* las_t;

__device__ __forceinline__ void gload_lds16(const float* g, float* l) {
    __builtin_amdgcn_global_load_lds((gas_t)g, (las_t)l, 16, 0, 0);
}

#define RED5(v) { v += __shfl_xor(v, 16); v += __shfl_xor(v, 8); v += __shfl_xor(v, 4); \
                  v += __shfl_xor(v, 2);  v += __shfl_xor(v, 1); }

// generic zero-fill, 16B stores (the rocclr fillBuffer kernel runs at 27 GB/s
// on small fills — 130 us for 3.4 MB; this does it in ~4 us)
__global__ void zerofill(float4* __restrict__ o, int n4) {
    int i = blockIdx.x * blockDim.x + threadIdx.x;
    const int st = gridDim.x * blockDim.x;
    const float4 z = make_float4(0.f, 0.f, 0.f, 0.f);
    for (; i < n4; i += st) o[i] = z;
}

// K0: image [B][64][H][W] -> imgT [B][H][W][64]  (makes K1's gather coalesced)
__global__ __launch_bounds__(256) void transpose_cl(
    const float* __restrict__ img, float* __restrict__ imgT)
{
    __shared__ float t[64 * 257];            // +1 pad: conflict-free both phases
    const int b    = blockIdx.x / (HW / 256);
    const int tile = blockIdx.x % (HW / 256);
    const int hw0  = tile * 256;
    const int tid  = threadIdx.x;

    const float* base = img + (size_t)b * NCH * HW + hw0;
    #pragma unroll 4
    for (int c = 0; c < 64; ++c)
        t[c * 257 + tid] = base[(size_t)c * HW + tid];   // 1KB coalesced read / iter
    __syncthreads();

    float* ob = imgT + ((size_t)b * HW + hw0) * NCH;
    const int c = tid & 63, r = tid >> 6;
    #pragma unroll 4
    for (int it = 0; it < 64; ++it) {
        const int hw = it * 4 + r;
        ob[hw * 64 + c] = t[c * 257 + hw];               // 1KB coalesced write / iter
    }
}

// K1: encode + gated MLP. MODE 0: direct canvas scatter, plane-major image (full fallback)
//                         MODE 1: feat/idxmap out, plane-major image
//                         MODE 2: feat/idxmap out, channel-last imgT (primary)
template<int MODE>
__global__ __launch_bounds__(TPB, 4) void pillar_compute(
    const float* __restrict__ pillars, const int* __restrict__ coors,
    const int* __restrict__ npp, const float* __restrict__ image,
    const float* __restrict__ calibs, const float* __restrict__ conv_w,
    const float* __restrict__ bng, const float* __restrict__ bnb,
    const float* __restrict__ bnm, const float* __restrict__ bnv,
    const float* __restrict__ w1, const float* __restrict__ b1,
    const float* __restrict__ lng, const float* __restrict__ lnb,
    const float* __restrict__ w2, const float* __restrict__ b2,
    float* __restrict__ feat, int* __restrict__ idxmap,
    float* __restrict__ out, int P)
{
    __shared__ float w1p[128 * WPITCH];      // 66 KB: w1p[j*WPITCH+k] = w1[j][k]
    __shared__ float w2p[64 * WPITCH];       // 33 KB
    __shared__ float ws[WAVES][512];         // 2 KB/wave: points -> cat -> g

    const int tid  = threadIdx.x;
    const int lane = tid & 63;
    const int wv   = tid >> 6;

    for (int i = tid; i < 128 * 32; i += TPB) {
        const int j = i >> 5, k4 = i & 31;
        ((float4*)(w1p + j * WPITCH))[k4] = ((const float4*)w1)[i];
    }
    for (int i = tid; i < 64 * 32; i += TPB) {
        const int j = i >> 5, k4 = i & 31;
        ((float4*)(w2p + j * WPITCH))[k4] = ((const float4*)w2)[i];
    }
    __syncthreads();

    // ---- per-channel folded conv+BN constants (lane = channel) ----
    float cw[9];
    #pragma unroll
    for (int i = 0; i < 9; ++i) cw[i] = conv_w[lane * 9 + i];
    const float s   = bng[lane] / sqrtf(bnv[lane] + 1e-3f);
    const float tch = bnb[lane] - bnm[lane] * s;      // BN(0): masked-row value
    const float As  = (cw[0] + cw[4] + cw[7]) * s;
    const float Bs  = (cw[1] + cw[5] + cw[8]) * s;
    const float Cs  = (cw[2] + cw[6]) * s;
    const float Ds  = cw[3] * s;
    const float w07 = (cw[0] + cw[7]) * s;
    const float w18 = (cw[1] + cw[8]) * s;
    const float w4s = cw[4] * s, w5s = cw[5] * s, w6s = cw[6] * s;

    const float b1a = b1[lane], b1b = b1[lane + 64];
    const float lga = lng[lane], lgb = lng[lane + 64];
    const float lba = lnb[lane], lbb = lnb[lane + 64];
    const float gb2 = b2[lane];

    float* wsw = ws[wv];
    const float4* wsf4 = (const float4*)wsw;
    const float4* w1rA = (const float4*)(w1p + lane * WPITCH);
    const float4* w1rB = (const float4*)(w1p + (lane + 64) * WPITCH);
    const float4* w2r  = (const float4*)(w2p + lane * WPITCH);

    const int ntasks = (P + PPG - 1) / PPG;

    for (int grp = blockIdx.x * WAVES + wv; grp < ntasks; grp += NBLOCKS * WAVES) {
        const int pbase = grp * PPG;
        const bool full = (pbase + PPG <= P);

        // ---------- stage 4 pillars' points (2 KB) into ws ----------
        asm volatile("s_waitcnt lgkmcnt(0)" ::: "memory");  // prior-iter LDS reads done
        if (full) {
            const float* src = pillars + (size_t)pbase * (PTS_M * 4);
            gload_lds16(src + lane * 4, wsw);
            gload_lds16(src + 256 + lane * 4, wsw + 256);
        } else {
            #pragma unroll
            for (int h = 0; h < 2; ++h) {
                const int idx = pbase * PTS_M + h * 64 + lane;
                float4 v = make_float4(0.f, 0.f, 0.f, 0.f);
                if (idx < P * PTS_M) v = ((const float4*)pillars)[idx];
                ((float4*)wsw)[h * 64 + lane] = v;
            }
        }

        int bbv[PPG], ixv[PPG], iyv[PPG], nv[PPG];
        #pragma unroll
        for (int pp = 0; pp < PPG; ++pp) {
            const int p = pbase + pp;
            if (p < P) {
                bbv[pp] = coors[p * 3]; ixv[pp] = coors[p * 3 + 1];
                iyv[pp] = coors[p * 3 + 2]; nv[pp] = npp[p];
            } else { bbv[pp] = 0; ixv[pp] = 0; iyv[pp] = 0; nv[pp] = 1; }
        }

        asm volatile("s_waitcnt vmcnt(0) lgkmcnt(0)" ::: "memory");  // points in LDS

        // ---------- means: pairwise half-wave reductions ----------
        const float4 qa = wsf4[lane];
        const float4 qb = wsf4[64 + lane];
        float ax = qa.x, ay = qa.y, az = qa.z;
        float bx = qb.x, by = qb.y, bz = qb.z;
        RED5(ax) RED5(ay) RED5(az)
        RED5(bx) RED5(by) RED5(bz)
        const float axo = __shfl_xor(ax, 32), ayo = __shfl_xor(ay, 32), azo = __shfl_xor(az, 32);
        const float bxo = __shfl_xor(bx, 32), byo = __shfl_xor(by, 32), bzo = __shfl_xor(bz, 32);
        const bool lo = lane < 32;
        float mx[PPG], my[PPG], mz[PPG];
        {
            const float f0 = 1.f / (float)nv[0], f1 = 1.f / (float)nv[1];
            const float f2 = 1.f / (float)nv[2], f3 = 1.f / (float)nv[3];
            mx[0] = (lo ? ax : axo) * f0;  mx[1] = (lo ? axo : ax) * f1;
            my[0] = (lo ? ay : ayo) * f0;  my[1] = (lo ? ayo : ay) * f1;
            mz[0] = (lo ? az : azo) * f0;  mz[1] = (lo ? azo : az) * f1;
            mx[2] = (lo ? bx : bxo) * f2;  mx[3] = (lo ? bxo : bx) * f3;
            my[2] = (lo ? by : byo) * f2;  my[3] = (lo ? byo : by) * f3;
            mz[2] = (lo ? bz : bzo) * f2;  mz[3] = (lo ? bzo : bz) * f3;
        }

        // ---------- projection + image gather issue + folded bias ----------
        float img[PPG], Es[PPG];
        #pragma unroll
        for (int pp = 0; pp < PPG; ++pp) {
            const float* cb = calibs + bbv[pp] * 12;
            const float pr0 = cb[0]*mx[pp] + cb[1]*my[pp] + cb[2]*mz[pp] + cb[3];
            const float pr1 = cb[4]*mx[pp] + cb[5]*my[pp] + cb[6]*mz[pp] + cb[7];
            const float pr2 = cb[8]*mx[pp] + cb[9]*my[pp] + cb[10]*mz[pp] + cb[11];
            float uf = (pr0 / pr2) * 0.5f;
            float vf = (pr1 / pr2) * 0.5f;
            uf = fminf(fmaxf(uf, 0.f), (float)(WIMG - 1));
            vf = fminf(fmaxf(vf, 0.f), (float)(HIMG - 1));
            const int u = (int)uf, v = (int)vf;
            if (MODE == 2) {
                // channel-last: 64 lanes read 256 contiguous bytes (coalesced)
                img[pp] = image[((size_t)bbv[pp] * HW + (size_t)v * WIMG + u) * NCH + lane];
            } else {
                img[pp] = image[(((size_t)(bbv[pp] * NCH + lane)) * HIMG + v) * WIMG + u];
            }
            const float cxp = (float)ixv[pp] * 0.16f + 0.08f;
            const float cyp = (float)iyv[pp] * 0.16f + (-39.6f);
            Es[pp] = tch - (cxp * w07 + cyp * w18 + mx[pp] * w4s + my[pp] * w5s + mz[pp] * w6s);
        }

        // ---------- pooled max: LDS broadcast reads ----------
        float pooled[PPG];
        #pragma unroll
        for (int pp = 0; pp < PPG; ++pp) {
            const int n = nv[pp];
            float p0 = (n < PTS_M) ? tch : -FLT_MAX;
            float p1 = -FLT_MAX, p2 = -FLT_MAX, p3 = -FLT_MAX;
            #pragma unroll
            for (int m = 0; m < PTS_M; m += 4) {
                const float4 q0 = wsf4[pp * 32 + m];
                const float4 q1 = wsf4[pp * 32 + m + 1];
                const float4 q2 = wsf4[pp * 32 + m + 2];
                const float4 q3 = wsf4[pp * 32 + m + 3];
                const float h0 = Es[pp] + q0.x*As + q0.y*Bs + q0.z*Cs + q0.w*Ds;
                const float h1 = Es[pp] + q1.x*As + q1.y*Bs + q1.z*Cs + q1.w*Ds;
                const float h2 = Es[pp] + q2.x*As + q2.y*Bs + q2.z*Cs + q2.w*Ds;
                const float h3 = Es[pp] + q3.x*As + q3.y*Bs + q3.z*Cs + q3.w*Ds;
                p0 = fmaxf(p0, (m     < n) ? h0 : -FLT_MAX);
                p1 = fmaxf(p1, (m + 1 < n) ? h1 : -FLT_MAX);
                p2 = fmaxf(p2, (m + 2 < n) ? h2 : -FLT_MAX);
                p3 = fmaxf(p3, (m + 3 < n) ? h3 : -FLT_MAX);
            }
            pooled[pp] = fmaxf(fmaxf(fmaxf(p0, p1), fmaxf(p2, p3)), 0.f);
        }

        // ---------- cat -> ws ----------
        #pragma unroll
        for (int pp = 0; pp < PPG; ++pp) {
            wsw[pp * 128 + lane]      = pooled[pp];
            wsw[pp * 128 + 64 + lane] = img[pp];
        }
        asm volatile("s_waitcnt lgkmcnt(0)" ::: "memory");

        // ---------- GEMM1 ----------
        float accA[PPG], accB[PPG];
        #pragma unroll
        for (int pp = 0; pp < PPG; ++pp) { accA[pp] = b1a; accB[pp] = b1b; }
        #pragma unroll 4
        for (int k4 = 0; k4 < 32; ++k4) {
            const float4 wa = w1rA[k4];
            const float4 wb = w1rB[k4];
            #pragma unroll
            for (int pp = 0; pp < PPG; ++pp) {
                const float4 cv = wsf4[pp * 32 + k4];
                accA[pp] += cv.x*wa.x + cv.y*wa.y + cv.z*wa.z + cv.w*wa.w;
                accB[pp] += cv.x*wb.x + cv.y*wb.y + cv.z*wb.z + cv.w*wb.w;
            }
        }

        // ---------- LayerNorm(128) + relu -> ws ----------
        float sum[PPG], sq[PPG];
        #pragma unroll
        for (int pp = 0; pp < PPG; ++pp) {
            sum[pp] = accA[pp] + accB[pp];
            sq[pp]  = accA[pp]*accA[pp] + accB[pp]*accB[pp];
        }
        #pragma unroll
        for (int d = 32; d; d >>= 1) {
            #pragma unroll
            for (int pp = 0; pp < PPG; ++pp) {
                sum[pp] += __shfl_xor(sum[pp], d);
                sq[pp]  += __shfl_xor(sq[pp], d);
            }
        }
        #pragma unroll
        for (int pp = 0; pp < PPG; ++pp) {
            const float mu  = sum[pp] * (1.f / 128.f);
            const float var = sq[pp] * (1.f / 128.f) - mu * mu;
            const float inv = 1.f / sqrtf(var + 1e-5f);
            const float g0 = (accA[pp] - mu) * inv * lga + lba;
            const float g1 = (accB[pp] - mu) * inv * lgb + lbb;
            wsw[pp * 128 + lane]      = fmaxf(g0, 0.f);
            wsw[pp * 128 + 64 + lane] = fmaxf(g1, 0.f);
        }
        asm volatile("s_waitcnt lgkmcnt(0)" ::: "memory");

        // ---------- GEMM2 + gate + output ----------
        float ac2[PPG];
        #pragma unroll
        for (int pp = 0; pp < PPG; ++pp) ac2[pp] = gb2;
        #pragma unroll 4
        for (int k4 = 0; k4 < 32; ++k4) {
            const float4 w = w2r[k4];
            #pragma unroll
            for (int pp = 0; pp < PPG; ++pp) {
                const float4 gv = wsf4[pp * 32 + k4];
                ac2[pp] += gv.x*w.x + gv.y*w.y + gv.z*w.z + gv.w*w.w;
            }
        }
        #pragma unroll
        for (int pp = 0; pp < PPG; ++pp) {
            const int p = pbase + pp;
            if (p >= P) continue;
            const float gate = 1.f / (1.f + expf(-ac2[pp]));
            const float gf = pooled[pp] * gate + img[pp] * (1.f - gate);
            if (MODE == 0) {
                out[(((bbv[pp] * NCH) + lane) * YL + iyv[pp]) * XL + ixv[pp]] = gf;
            } else {
                feat[(size_t)p * NCH + lane] = gf;              // coalesced 256B
                if (lane == 0)
                    idxmap[(bbv[pp] * YL + iyv[pp]) * XL + ixv[pp]] = p + 1;
            }
        }
    }
}

// K2: stream the canvas with full-line stores (fuses zero-fill; no RFO grain)
__global__ __launch_bounds__(256) void canvas_build(
    const float* __restrict__ feat, const int* __restrict__ idxmap,
    float4* __restrict__ out)
{
    __shared__ int idxrow[XL];
    const int by = blockIdx.x;              // b*YL + y
    const int b = by / YL, y = by % YL;
    const int* irow = idxmap + (size_t)by * XL;
    for (int i = threadIdx.x; i < XL; i += 256) idxrow[i] = irow[i];
    __syncthreads();

    const int NF4 = XL / 4;                 // 108
    for (int t = threadIdx.x; t < NCH * NF4; t += 256) {
        const int c = t / NF4, x4 = t - c * NF4;
        const int i0 = idxrow[x4*4+0], i1 = idxrow[x4*4+1];
        const int i2 = idxrow[x4*4+2], i3 = idxrow[x4*4+3];
        float4 o = make_float4(0.f, 0.f, 0.f, 0.f);
        if (i0) o.x = feat[(size_t)(i0-1) * NCH + c];
        if (i1) o.y = feat[(size_t)(i1-1) * NCH + c];
        if (i2) o.z = feat[(size_t)(i2-1) * NCH + c];
        if (i3) o.w = feat[(size_t)(i3-1) * NCH + c];
        out[((size_t)(b * NCH + c) * YL + y) * NF4 + x4] = o;
    }
}

extern "C" void kernel_launch(void* const* d_in, const int* in_sizes, int n_in,
                              void* d_out, int out_size, void* d_ws, size_t ws_size,
                              hipStream_t stream)
{
    const float* pillars = (const float*)d_in[0];
    const int*   coors   = (const int*)d_in[1];
    const int*   npp     = (const int*)d_in[2];
    const float* image   = (const float*)d_in[3];
    const float* calibs  = (const float*)d_in[4];
    const float* conv_w  = (const float*)d_in[6];
    const float* bng     = (const float*)d_in[7];
    const float* bnb     = (const float*)d_in[8];
    const float* bnm     = (const float*)d_in[9];
    const float* bnv     = (const float*)d_in[10];
    const float* w1      = (const float*)d_in[11];
    const float* b1      = (const float*)d_in[12];
    const float* lng     = (const float*)d_in[13];
    const float* lnb     = (const float*)d_in[14];
    const float* w2      = (const float*)d_in[15];
    const float* b2      = (const float*)d_in[16];
    float* out = (float*)d_out;
    const int P = in_sizes[0] / (PTS_M * 4);
    const int B = in_sizes[3] / (NCH * HW);

    const size_t featBytes = (size_t)P * NCH * sizeof(float);        // 10.24 MB
    const size_t idxBytes  = (size_t)B * YL * XL * sizeof(int);      //  3.43 MB (16B-mult: B*YL*XL % 4 == 0)
    const size_t imgTBytes = (size_t)B * HW * NCH * sizeof(float);   // 125.8 MB

    if (ws_size >= featBytes + idxBytes + imgTBytes) {
        float* feat   = (float*)d_ws;
        int*   idxmap = (int*)((char*)d_ws + featBytes);
        float* imgT   = (float*)((char*)d_ws + featBytes + idxBytes);
        // own zero-fill: rocclr fillBufferAligned runs at 27 GB/s on small fills (130us!)
        zerofill<<<dim3(880), dim3(256), 0, stream>>>((float4*)idxmap, (int)(idxBytes / 16));
        transpose_cl<<<dim3(B * (HW / 256)), dim3(256), 0, stream>>>(image, imgT);
        pillar_compute<2><<<dim3(NBLOCKS), dim3(TPB), 0, stream>>>(
            pillars, coors, npp, imgT, calibs, conv_w, bng, bnb, bnm, bnv,
            w1, b1, lng, lnb, w2, b2, feat, idxmap, nullptr, P);
        canvas_build<<<dim3(B * YL), dim3(256), 0, stream>>>(feat, idxmap, (float4*)d_out);
    } else if (ws_size >= featBytes + idxBytes) {
        float* feat   = (float*)d_ws;
        int*   idxmap = (int*)((char*)d_ws + featBytes);
        zerofill<<<dim3(880), dim3(256), 0, stream>>>((float4*)idxmap, (int)(idxBytes / 16));
        pillar_compute<1><<<dim3(NBLOCKS), dim3(TPB), 0, stream>>>(
            pillars, coors, npp, image, calibs, conv_w, bng, bnb, bnm, bnv,
            w1, b1, lng, lnb, w2, b2, feat, idxmap, nullptr, P);
        canvas_build<<<dim3(B * YL), dim3(256), 0, stream>>>(feat, idxmap, (float4*)d_out);
    } else {
        zerofill<<<dim3(2048), dim3(256), 0, stream>>>((float4*)d_out, out_size / 4);
        pillar_compute<0><<<dim3(NBLOCKS), dim3(TPB), 0, stream>>>(
            pillars, coors, npp, image, calibs, conv_w, bng, bnb, bnm, bnv,
            w1, b1, lng, lnb, w2, b2, nullptr, nullptr, out, P);
    }
}